// Round 8
// baseline (146.521 us; speedup 1.0000x reference)
//
#include <hip/hip_runtime.h>

typedef __attribute__((ext_vector_type(8))) __bf16 bf16x8;
typedef __attribute__((ext_vector_type(4))) float f32x4;
typedef const __attribute__((address_space(1))) unsigned int gu32;
typedef __attribute__((address_space(3))) unsigned int lu32;

#define B_ 16
#define S_ 1024
#define D_ 1024
#define R_ 128

// Fire-and-forget 16B global->LDS DMA (no VGPR dest -> deep HW queue).
__device__ __forceinline__ void gl16(const void* g, void* l) {
    __builtin_amdgcn_global_load_lds((gu32*)g, (lu32*)l, 16, 0, 0);
}

// proj [D][R] fp32  ->  projT [R][D] bf16  (transpose + cast, LDS tiled)
__global__ __launch_bounds__(256) void k_transpose(const float* __restrict__ proj,
                                                   __bf16* __restrict__ projT) {
    __shared__ __bf16 tile[64][66];
    const int k0 = blockIdx.x * 64;
    const int r0 = blockIdx.y * 64;
#pragma unroll
    for (int it = 0; it < 16; ++it) {
        int idx = it * 256 + threadIdx.x;
        int kk = idx >> 6, rr = idx & 63;
        tile[kk][rr] = (__bf16)proj[(size_t)(k0 + kk) * R_ + (r0 + rr)];
    }
    __syncthreads();
#pragma unroll
    for (int it = 0; it < 16; ++it) {
        int idx = it * 256 + threadIdx.x;
        int rr = idx >> 6, kk = idx & 63;
        projT[(size_t)(r0 + rr) * D_ + (k0 + kk)] = tile[kk][rr];
    }
}

// t = batch @ proj. v10: DEPTH-4 DMA pipeline. Same tile/math as v8 (16 rows
// x 128 cols, 4 waves split N, BK=64, identical swizzles & accumulation order)
// but quad-buffered LDS (4 x 20KB = 80KB -> 2 blocks/CU): prologue stages
// chunks 0..2; steady state issues chunk c+3 then waits vmcnt(15) (= chunks
// c+1..c+3 / 15 DMAs stay in flight). Issue-to-use lead = 3 chunk-periods
// (~900+ cyc), covering HBM latency. v8's depth-2 lead (~300 cyc) exposed
// ~600 cyc of stall per chunk (why counted-vmcnt alone gave only -2.7us).
__global__ __launch_bounds__(256, 2) void k_proj(const float* __restrict__ batch,
                                                 const __bf16* __restrict__ projT,
                                                 __bf16* __restrict__ t,
                                                 float* __restrict__ sqn) {
    __shared__ __align__(16) char smem[81920];   // A: 4x4KB @0, B: 4x16KB @16384
    const int wave = threadIdx.x >> 6;
    const int lane = threadIdx.x & 63;
    const int ln = lane & 15, q = lane >> 4;
    const int m0 = blockIdx.x * 16;

    const int arow = wave * 4 + (lane >> 4);                   // A row 0..15
    const int aswz = ((arow & 7) << 5) | ((arow & 8) << 1);
    const char* ag = (const char*)batch + (size_t)(m0 + arow) * 4096
                   + (((lane & 15) * 16) ^ aswz);
    const int brx = wave * 8 + (lane >> 3);                    // B row base 0..31 (+s*32)
    const int bswz = (brx & 7) << 4;
    const char* bg = (const char*)projT + (size_t)brx * 2048
                   + (((lane & 7) * 16) ^ bswz);
    char* const abuf0 = smem + wave * 1024;                    // + buf*4096
    char* const bbuf0 = smem + 16384 + wave * 1024;            // + buf*16384

    const int raswz = ((ln & 7) << 5) | ((ln & 8) << 1);
    const int rbswz = (ln & 7) << 4;
    const int kq = q * 32;
    const int kq2 = q * 16;

    f32x4 acc[2];
    acc[0] = f32x4{0.f, 0.f, 0.f, 0.f};
    acc[1] = f32x4{0.f, 0.f, 0.f, 0.f};

#define STAGE_P(c, buf)                                                      \
    do {                                                                     \
        gl16(ag + (c) * 256, abuf0 + (buf) * 4096);                          \
        gl16(bg + (c) * 128,                 bbuf0 + (buf) * 16384);         \
        gl16(bg + 32 * 2048 + (c) * 128,     bbuf0 + (buf) * 16384 + 4096);  \
        gl16(bg + 64 * 2048 + (c) * 128,     bbuf0 + (buf) * 16384 + 8192);  \
        gl16(bg + 96 * 2048 + (c) * 128,     bbuf0 + (buf) * 16384 + 12288); \
    } while (0)

    STAGE_P(0, 0);
    STAGE_P(1, 1);
    STAGE_P(2, 2);   // 15 DMAs in flight
#pragma unroll
    for (int c = 0; c < 16; ++c) {
        const int buf = c & 3;
        if (c < 13) {
            STAGE_P(c + 3, (c + 3) & 3);                       // 20 outstanding
            asm volatile("s_waitcnt vmcnt(15)" ::: "memory");  // chunk c landed
        } else if (c == 13) {
            asm volatile("s_waitcnt vmcnt(10)" ::: "memory");
        } else if (c == 14) {
            asm volatile("s_waitcnt vmcnt(5)" ::: "memory");
        } else {
            asm volatile("s_waitcnt vmcnt(0)" ::: "memory");
        }
        __builtin_amdgcn_s_barrier();   // all waves' chunk-c DMAs retired
        const char* ab = smem + buf * 4096 + ln * 256;
        const char* bb = smem + 16384 + buf * 16384 + ln * 128;
#pragma unroll
        for (int ks = 0; ks < 2; ++ks) {
            float4 lo = *(const float4*)(ab + ((ks * 128 + kq) ^ raswz));
            float4 hi = *(const float4*)(ab + ((ks * 128 + kq + 16) ^ raswz));
            bf16x8 af;
            af[0] = (__bf16)lo.x; af[1] = (__bf16)lo.y;
            af[2] = (__bf16)lo.z; af[3] = (__bf16)lo.w;
            af[4] = (__bf16)hi.x; af[5] = (__bf16)hi.y;
            af[6] = (__bf16)hi.z; af[7] = (__bf16)hi.w;
            const int ko = (ks * 64 + kq2) ^ rbswz;
            bf16x8 bf0 = *(const bf16x8*)(bb + (wave * 2 + 0) * 2048 + ko);
            bf16x8 bf1 = *(const bf16x8*)(bb + (wave * 2 + 1) * 2048 + ko);
            acc[0] = __builtin_amdgcn_mfma_f32_16x16x32_bf16(af, bf0, acc[0], 0, 0, 0);
            acc[1] = __builtin_amdgcn_mfma_f32_16x16x32_bf16(af, bf1, acc[1], 0, 0, 0);
        }
        __builtin_amdgcn_s_barrier();   // buf free; next iter may re-stage it
    }
#undef STAGE_P

    // ---- epilogue: identical to v8 (each wave owns ni = wave*2+p) ----
    float* sqpart = (float*)smem;
    float sq[4] = {0.f, 0.f, 0.f, 0.f};
#pragma unroll
    for (int p = 0; p < 2; ++p) {
        const int ni = wave * 2 + p;
        f32x4 v = acc[p];
#pragma unroll
        for (int r = 0; r < 4; ++r) {
            __bf16 h = (__bf16)v[r];
            t[(size_t)(m0 + q * 4 + r) * R_ + ni * 16 + ln] = h;
            float f = (float)h;
            sq[r] += f * f;  // sq_norm from rounded t: keeps diagonal exact vs gram
        }
    }
#pragma unroll
    for (int r = 0; r < 4; ++r) {
#pragma unroll
        for (int off = 1; off < 16; off <<= 1)
            sq[r] += __shfl_xor(sq[r], off, 64);
    }
    if (ln == 0) {
#pragma unroll
        for (int r = 0; r < 4; ++r) sqpart[wave * 16 + q * 4 + r] = sq[r];
    }
    __syncthreads();
    if (threadIdx.x < 16) {
        float s = sqpart[threadIdx.x] + sqpart[16 + threadIdx.x] +
                  sqpart[32 + threadIdx.x] + sqpart[48 + threadIdx.x];
        sqn[m0 + threadIdx.x] = s;
    }
}

// Per batch: cross = t @ t^T; out = max(0, sqn_i + sqn_j - 2*cross).
// v8 form (R6-verified, REVERTED from v9's symmetry split which regressed):
// full 8x8 block grid; 2-half counted-vmcnt stage; NT stores.
__global__ __launch_bounds__(256, 2) void k_gram(const __bf16* __restrict__ t,
                                                 const float* __restrict__ sqn,
                                                 float* __restrict__ out) {
    __shared__ __align__(16) char smem[65536];
    const int b = blockIdx.z;
    const int wave = threadIdx.x >> 6, lane = threadIdx.x & 63;
    const int ln = lane & 15, q = lane >> 4;
    const int wi = wave >> 1, wj = wave & 1;
    const int i0b = blockIdx.y * 128, j0b = blockIdx.x * 128;
    const __bf16* tb = t + (size_t)b * S_ * R_;
    const float* sqb = sqn + (size_t)b * S_;

    float sqj[4];
#pragma unroll
    for (int ni = 0; ni < 4; ++ni) sqj[ni] = sqb[j0b + wj * 64 + ni * 16 + ln];

    const int grow = wave * 8 + (lane >> 3);     // 0..31
    const int goff = ((lane & 7) * 16) ^ ((grow & 7) << 4);
    const char* agt = (const char*)tb + (size_t)(i0b + grow) * 256 + goff;
    const char* bgt = (const char*)tb + (size_t)(j0b + grow) * 256 + goff;
    char* const adst = smem + wave * 1024;
    char* const bdst = smem + 16384 + wave * 1024;

#define STAGE_G(h)                                                        \
    do {                                                                  \
        gl16(agt + (h) * 128,              adst + (h) * 32768);           \
        gl16(agt + 32 * 256 + (h) * 128,   adst + (h) * 32768 + 4096);    \
        gl16(agt + 64 * 256 + (h) * 128,   adst + (h) * 32768 + 8192);    \
        gl16(agt + 96 * 256 + (h) * 128,   adst + (h) * 32768 + 12288);   \
        gl16(bgt + (h) * 128,              bdst + (h) * 32768);           \
        gl16(bgt + 32 * 256 + (h) * 128,   bdst + (h) * 32768 + 4096);    \
        gl16(bgt + 64 * 256 + (h) * 128,   bdst + (h) * 32768 + 8192);    \
        gl16(bgt + 96 * 256 + (h) * 128,   bdst + (h) * 32768 + 12288);   \
    } while (0)

    STAGE_G(0);
    STAGE_G(1);
#undef STAGE_G

    f32x4 acc[4][4];
#pragma unroll
    for (int mi = 0; mi < 4; ++mi)
#pragma unroll
        for (int ni = 0; ni < 4; ++ni) acc[mi][ni] = f32x4{0.f, 0.f, 0.f, 0.f};

    const int rsw = (ln & 7) << 4;
    const char* abA = smem + (size_t)(wi * 64 + ln) * 128;
    const char* abB = smem + 16384 + (size_t)(wj * 64 + ln) * 128;

#pragma unroll
    for (int h = 0; h < 2; ++h) {
        if (h == 0)
            asm volatile("s_waitcnt vmcnt(8)" ::: "memory");
        else
            asm volatile("s_waitcnt vmcnt(0)" ::: "memory");
        __builtin_amdgcn_s_barrier();
        const char* hA = abA + h * 32768;
        const char* hB = abB + h * 32768;
#pragma unroll
        for (int ks = 0; ks < 2; ++ks) {
            const int ko = (ks * 64 + q * 16) ^ rsw;
            bf16x8 af[4], bfm[4];
#pragma unroll
            for (int mi = 0; mi < 4; ++mi)
                af[mi] = *(const bf16x8*)(hA + mi * 2048 + ko);
#pragma unroll
            for (int ni = 0; ni < 4; ++ni)
                bfm[ni] = *(const bf16x8*)(hB + ni * 2048 + ko);
#pragma unroll
            for (int mi = 0; mi < 4; ++mi)
#pragma unroll
                for (int ni = 0; ni < 4; ++ni)
                    acc[mi][ni] = __builtin_amdgcn_mfma_f32_16x16x32_bf16(
                        af[mi], bfm[ni], acc[mi][ni], 0, 0, 0);
        }
    }

    const int i0 = i0b + wi * 64, j0 = j0b + wj * 64;
    float* outb = out + (size_t)b * S_ * S_;
#pragma unroll
    for (int mi = 0; mi < 4; ++mi) {
#pragma unroll
        for (int r = 0; r < 4; ++r) {
            const int i = i0 + mi * 16 + q * 4 + r;
            const float si = sqb[i];
            float* orow = outb + (size_t)i * S_ + j0;
#pragma unroll
            for (int ni = 0; ni < 4; ++ni) {
                float v = si + sqj[ni] - 2.f * acc[mi][ni][r];
                __builtin_nontemporal_store(fmaxf(v, 0.f), &orow[ni * 16 + ln]);
            }
        }
    }
}

extern "C" void kernel_launch(void* const* d_in, const int* in_sizes, int n_in,
                              void* d_out, int out_size, void* d_ws, size_t ws_size,
                              hipStream_t stream) {
    const float* batch = (const float*)d_in[0];  // [16,1024,1024] fp32
    const float* proj  = (const float*)d_in[1];  // [1024,128] fp32
    float* out = (float*)d_out;                  // [16,1024,1024] fp32

    char* ws = (char*)d_ws;
    __bf16* t     = (__bf16*)ws;                                   // 16384x128 bf16 = 4 MB
    __bf16* projT = (__bf16*)(ws + (size_t)B_ * S_ * R_ * 2);      // 128x1024 bf16 = 256 KB
    float*  sqn   = (float*)(ws + (size_t)B_ * S_ * R_ * 2
                                + (size_t)R_ * D_ * 2);            // 16384 fp32 = 64 KB

    k_transpose<<<dim3(D_ / 64, R_ / 64), 256, 0, stream>>>(proj, projT);
    k_proj<<<dim3((B_ * S_) / 16), 256, 0, stream>>>(batch, projT, t, sqn);
    k_gram<<<dim3(S_ / 128, S_ / 128, B_), 256, 0, stream>>>(t, sqn, out);
}

// Round 9
// 140.223 us; speedup vs baseline: 1.0449x; 1.0449x over previous
//
#include <hip/hip_runtime.h>

typedef __attribute__((ext_vector_type(8))) __bf16 bf16x8;
typedef __attribute__((ext_vector_type(4))) float f32x4;
typedef const __attribute__((address_space(1))) unsigned int gu32;
typedef __attribute__((address_space(3))) unsigned int lu32;

#define B_ 16
#define S_ 1024
#define D_ 1024
#define R_ 128

// Fire-and-forget 16B global->LDS DMA (no VGPR dest -> deep HW queue).
__device__ __forceinline__ void gl16(const void* g, void* l) {
    __builtin_amdgcn_global_load_lds((gu32*)g, (lu32*)l, 16, 0, 0);
}

// proj [D][R] fp32  ->  projT [R][D] bf16  (transpose + cast, LDS tiled)
__global__ __launch_bounds__(256) void k_transpose(const float* __restrict__ proj,
                                                   __bf16* __restrict__ projT) {
    __shared__ __bf16 tile[64][66];
    const int k0 = blockIdx.x * 64;
    const int r0 = blockIdx.y * 64;
#pragma unroll
    for (int it = 0; it < 16; ++it) {
        int idx = it * 256 + threadIdx.x;
        int kk = idx >> 6, rr = idx & 63;
        tile[kk][rr] = (__bf16)proj[(size_t)(k0 + kk) * R_ + (r0 + rr)];
    }
    __syncthreads();
#pragma unroll
    for (int it = 0; it < 16; ++it) {
        int idx = it * 256 + threadIdx.x;
        int rr = idx >> 6, kk = idx & 63;
        projT[(size_t)(r0 + rr) * D_ + (k0 + kk)] = tile[kk][rr];
    }
}

// t = batch @ proj. v8 (RESTORED, R6-verified session best, 138.5us total):
// 16 rows x 128 cols, 4 waves split N, BK=64, 40KB LDS dbuf -> 4 blocks/CU,
// counted-vmcnt sync (s_waitcnt vmcnt(5) + raw s_barrier; never drain to 0
// in the main loop). Depth-4 (v10) and 512-thr/BK=128 (v7) variants both
// REGRESSED: losing 4-blocks/CU cross-block overlap costs more than deeper
// within-block pipelining buys. This config is the measured optimum.
//   A [16][64]f32 (256B rows):  byte ^= ((row&7)<<5)|((row&8)<<1)
//   B [128][64]bf16 (128B rows): byte ^= ((row&7)<<4)
__global__ __launch_bounds__(256, 4) void k_proj(const float* __restrict__ batch,
                                                 const __bf16* __restrict__ projT,
                                                 __bf16* __restrict__ t,
                                                 float* __restrict__ sqn) {
    __shared__ __align__(16) char smem[40960];
    const int wave = threadIdx.x >> 6;
    const int lane = threadIdx.x & 63;
    const int ln = lane & 15, q = lane >> 4;
    const int m0 = blockIdx.x * 16;

    const int arow = wave * 4 + (lane >> 4);                   // A row 0..15
    const int aswz = ((arow & 7) << 5) | ((arow & 8) << 1);
    const char* ag = (const char*)batch + (size_t)(m0 + arow) * 4096
                   + (((lane & 15) * 16) ^ aswz);
    const int brx = wave * 8 + (lane >> 3);                    // B row base 0..31 (+s*32)
    const int bswz = (brx & 7) << 4;
    const char* bg = (const char*)projT + (size_t)brx * 2048
                   + (((lane & 7) * 16) ^ bswz);
    char* const abuf0 = smem + wave * 1024;
    char* const bbuf0 = smem + 8192 + wave * 1024;

    const int raswz = ((ln & 7) << 5) | ((ln & 8) << 1);
    const int rbswz = (ln & 7) << 4;
    const int kq = q * 32;
    const int kq2 = q * 16;

    f32x4 acc[2];
    acc[0] = f32x4{0.f, 0.f, 0.f, 0.f};
    acc[1] = f32x4{0.f, 0.f, 0.f, 0.f};

#define STAGE_P(c, buf)                                                      \
    do {                                                                     \
        gl16(ag + (c) * 256, abuf0 + (buf) * 4096);                          \
        gl16(bg + (c) * 128,                 bbuf0 + (buf) * 16384);         \
        gl16(bg + 32 * 2048 + (c) * 128,     bbuf0 + (buf) * 16384 + 4096);  \
        gl16(bg + 64 * 2048 + (c) * 128,     bbuf0 + (buf) * 16384 + 8192);  \
        gl16(bg + 96 * 2048 + (c) * 128,     bbuf0 + (buf) * 16384 + 12288); \
    } while (0)

    STAGE_P(0, 0);
#pragma unroll
    for (int c = 0; c < 16; ++c) {
        const int buf = c & 1;
        if (c < 15) {
            STAGE_P(c + 1, buf ^ 1);
            asm volatile("s_waitcnt vmcnt(5)" ::: "memory");  // chunk c landed; c+1 in flight
        } else {
            asm volatile("s_waitcnt vmcnt(0)" ::: "memory");
        }
        __builtin_amdgcn_s_barrier();   // all waves' chunk-c DMAs retired
        const char* ab = smem + buf * 4096 + ln * 256;
        const char* bb = smem + 8192 + buf * 16384 + ln * 128;
#pragma unroll
        for (int ks = 0; ks < 2; ++ks) {
            float4 lo = *(const float4*)(ab + ((ks * 128 + kq) ^ raswz));
            float4 hi = *(const float4*)(ab + ((ks * 128 + kq + 16) ^ raswz));
            bf16x8 af;
            af[0] = (__bf16)lo.x; af[1] = (__bf16)lo.y;
            af[2] = (__bf16)lo.z; af[3] = (__bf16)lo.w;
            af[4] = (__bf16)hi.x; af[5] = (__bf16)hi.y;
            af[6] = (__bf16)hi.z; af[7] = (__bf16)hi.w;
            const int ko = (ks * 64 + kq2) ^ rbswz;
            bf16x8 bf0 = *(const bf16x8*)(bb + (wave * 2 + 0) * 2048 + ko);
            bf16x8 bf1 = *(const bf16x8*)(bb + (wave * 2 + 1) * 2048 + ko);
            acc[0] = __builtin_amdgcn_mfma_f32_16x16x32_bf16(af, bf0, acc[0], 0, 0, 0);
            acc[1] = __builtin_amdgcn_mfma_f32_16x16x32_bf16(af, bf1, acc[1], 0, 0, 0);
        }
        __builtin_amdgcn_s_barrier();   // buf free for the next stage
    }
#undef STAGE_P

    float* sqpart = (float*)smem;
    float sq[4] = {0.f, 0.f, 0.f, 0.f};
#pragma unroll
    for (int p = 0; p < 2; ++p) {
        const int ni = wave * 2 + p;
        f32x4 v = acc[p];
#pragma unroll
        for (int r = 0; r < 4; ++r) {
            __bf16 h = (__bf16)v[r];
            t[(size_t)(m0 + q * 4 + r) * R_ + ni * 16 + ln] = h;
            float f = (float)h;
            sq[r] += f * f;  // sq_norm from rounded t: keeps diagonal exact vs gram
        }
    }
#pragma unroll
    for (int r = 0; r < 4; ++r) {
#pragma unroll
        for (int off = 1; off < 16; off <<= 1)
            sq[r] += __shfl_xor(sq[r], off, 64);
    }
    if (ln == 0) {
#pragma unroll
        for (int r = 0; r < 4; ++r) sqpart[wave * 16 + q * 4 + r] = sq[r];
    }
    __syncthreads();
    if (threadIdx.x < 16) {
        float s = sqpart[threadIdx.x] + sqpart[16 + threadIdx.x] +
                  sqpart[32 + threadIdx.x] + sqpart[48 + threadIdx.x];
        sqn[m0 + threadIdx.x] = s;
    }
}

// Per batch: cross = t @ t^T; out = max(0, sqn_i + sqn_j - 2*cross).
// v8 form (R6-verified): full 8x8 block grid; 2-half counted-vmcnt stage
// (no buffer reuse -> no race); NT stores. Symmetry-halving (v9) regressed:
// kernel is write-bound, and mirror-tile scattered stores cost more than the
// saved MFMA/stage work.
__global__ __launch_bounds__(256, 2) void k_gram(const __bf16* __restrict__ t,
                                                 const float* __restrict__ sqn,
                                                 float* __restrict__ out) {
    __shared__ __align__(16) char smem[65536];
    const int b = blockIdx.z;
    const int wave = threadIdx.x >> 6, lane = threadIdx.x & 63;
    const int ln = lane & 15, q = lane >> 4;
    const int wi = wave >> 1, wj = wave & 1;
    const int i0b = blockIdx.y * 128, j0b = blockIdx.x * 128;
    const __bf16* tb = t + (size_t)b * S_ * R_;
    const float* sqb = sqn + (size_t)b * S_;

    float sqj[4];
#pragma unroll
    for (int ni = 0; ni < 4; ++ni) sqj[ni] = sqb[j0b + wj * 64 + ni * 16 + ln];

    const int grow = wave * 8 + (lane >> 3);     // 0..31
    const int goff = ((lane & 7) * 16) ^ ((grow & 7) << 4);
    const char* agt = (const char*)tb + (size_t)(i0b + grow) * 256 + goff;
    const char* bgt = (const char*)tb + (size_t)(j0b + grow) * 256 + goff;
    char* const adst = smem + wave * 1024;
    char* const bdst = smem + 16384 + wave * 1024;

#define STAGE_G(h)                                                        \
    do {                                                                  \
        gl16(agt + (h) * 128,              adst + (h) * 32768);           \
        gl16(agt + 32 * 256 + (h) * 128,   adst + (h) * 32768 + 4096);    \
        gl16(agt + 64 * 256 + (h) * 128,   adst + (h) * 32768 + 8192);    \
        gl16(agt + 96 * 256 + (h) * 128,   adst + (h) * 32768 + 12288);   \
        gl16(bgt + (h) * 128,              bdst + (h) * 32768);           \
        gl16(bgt + 32 * 256 + (h) * 128,   bdst + (h) * 32768 + 4096);    \
        gl16(bgt + 64 * 256 + (h) * 128,   bdst + (h) * 32768 + 8192);    \
        gl16(bgt + 96 * 256 + (h) * 128,   bdst + (h) * 32768 + 12288);   \
    } while (0)

    STAGE_G(0);
    STAGE_G(1);
#undef STAGE_G

    f32x4 acc[4][4];
#pragma unroll
    for (int mi = 0; mi < 4; ++mi)
#pragma unroll
        for (int ni = 0; ni < 4; ++ni) acc[mi][ni] = f32x4{0.f, 0.f, 0.f, 0.f};

    const int rsw = (ln & 7) << 4;
    const char* abA = smem + (size_t)(wi * 64 + ln) * 128;
    const char* abB = smem + 16384 + (size_t)(wj * 64 + ln) * 128;

#pragma unroll
    for (int h = 0; h < 2; ++h) {
        if (h == 0)
            asm volatile("s_waitcnt vmcnt(8)" ::: "memory");
        else
            asm volatile("s_waitcnt vmcnt(0)" ::: "memory");
        __builtin_amdgcn_s_barrier();
        const char* hA = abA + h * 32768;
        const char* hB = abB + h * 32768;
#pragma unroll
        for (int ks = 0; ks < 2; ++ks) {
            const int ko = (ks * 64 + q * 16) ^ rsw;
            bf16x8 af[4], bfm[4];
#pragma unroll
            for (int mi = 0; mi < 4; ++mi)
                af[mi] = *(const bf16x8*)(hA + mi * 2048 + ko);
#pragma unroll
            for (int ni = 0; ni < 4; ++ni)
                bfm[ni] = *(const bf16x8*)(hB + ni * 2048 + ko);
#pragma unroll
            for (int mi = 0; mi < 4; ++mi)
#pragma unroll
                for (int ni = 0; ni < 4; ++ni)
                    acc[mi][ni] = __builtin_amdgcn_mfma_f32_16x16x32_bf16(
                        af[mi], bfm[ni], acc[mi][ni], 0, 0, 0);
        }
    }

    const int i0 = i0b + wi * 64, j0 = j0b + wj * 64;
    float* outb = out + (size_t)b * S_ * S_;
#pragma unroll
    for (int mi = 0; mi < 4; ++mi) {
#pragma unroll
        for (int r = 0; r < 4; ++r) {
            const int i = i0 + mi * 16 + q * 4 + r;
            const float si = sqb[i];
            float* orow = outb + (size_t)i * S_ + j0;
#pragma unroll
            for (int ni = 0; ni < 4; ++ni) {
                float v = si + sqj[ni] - 2.f * acc[mi][ni][r];
                __builtin_nontemporal_store(fmaxf(v, 0.f), &orow[ni * 16 + ln]);
            }
        }
    }
}

extern "C" void kernel_launch(void* const* d_in, const int* in_sizes, int n_in,
                              void* d_out, int out_size, void* d_ws, size_t ws_size,
                              hipStream_t stream) {
    const float* batch = (const float*)d_in[0];  // [16,1024,1024] fp32
    const float* proj  = (const float*)d_in[1];  // [1024,128] fp32
    float* out = (float*)d_out;                  // [16,1024,1024] fp32

    char* ws = (char*)d_ws;
    __bf16* t     = (__bf16*)ws;                                   // 16384x128 bf16 = 4 MB
    __bf16* projT = (__bf16*)(ws + (size_t)B_ * S_ * R_ * 2);      // 128x1024 bf16 = 256 KB
    float*  sqn   = (float*)(ws + (size_t)B_ * S_ * R_ * 2
                                + (size_t)R_ * D_ * 2);            // 16384 fp32 = 64 KB

    k_transpose<<<dim3(D_ / 64, R_ / 64), 256, 0, stream>>>(proj, projT);
    k_proj<<<dim3((B_ * S_) / 16), 256, 0, stream>>>(batch, projT, t, sqn);
    k_gram<<<dim3(S_ / 128, S_ / 128, B_), 256, 0, stream>>>(t, sqn, out);
}